// Round 7
// baseline (356.071 us; speedup 1.0000x reference)
//
#include <hip/hip_runtime.h>

// Problem constants (B=4, N=1024, DIM=1024, H=16, DH=64)
// Dtype model (r5-proven): tensor inputs fp32, masks int32, d_out fp32.
#define NTOK 4096
#define AST 72   // attn/transpose LDS row stride in halves (144 B = 16B-aligned, balanced banks)

typedef _Float16 half8 __attribute__((ext_vector_type(8)));
typedef float floatx4 __attribute__((ext_vector_type(4)));

__device__ __forceinline__ half8 cvt8(float4 a, float4 b) {
  half8 h;
  h[0] = (_Float16)a.x; h[1] = (_Float16)a.y; h[2] = (_Float16)a.z; h[3] = (_Float16)a.w;
  h[4] = (_Float16)b.x; h[5] = (_Float16)b.y; h[6] = (_Float16)b.z; h[7] = (_Float16)b.w;
  return h;
}

// ---------------------------------------------------------------------------
// Mask canonicalization (r3 proved masks arrive int32; kept for robustness).
// ---------------------------------------------------------------------------
__device__ __forceinline__ int mask_is_bytes(const int* p) {
  int bad = 0;
#pragma unroll
  for (int i = 0; i < 64; i++) bad |= (((unsigned int)p[i]) > 1u);
  return bad;
}

__global__ __launch_bounds__(256) void mask_prep(
    const int* __restrict__ srcQ, const int* __restrict__ srcK,
    int* __restrict__ dstQ, int* __restrict__ dstK)
{
  const int t = blockIdx.x * 256 + threadIdx.x;
  const int bq = mask_is_bytes(srcQ);
  const int bk = mask_is_bytes(srcK);
  dstQ[t] = bq ? (int)((const unsigned char*)srcQ)[t] : srcQ[t];
  dstK[t] = bk ? (int)((const unsigned char*)srcK)[t] : srcK[t];
}

// ---------------------------------------------------------------------------
// 128x64-tile f16-MFMA GEMM core (BK=32, 256 thr, 4 waves along M, 2x4 MFMA/wave).
// out[m,n] = sum_k X[m,k]*W[n,k]. Layouts (r2/r4-verified):
//   A: a[j]=A[m=l16][k=quad*8+j]; B: b[j]=B[n=l16][k=quad*8+j]; C: row=quad*4+reg, col=l16.
// Three epilogue variants: f32-masked (Qp), f16-masked (Kh/Vh), gelu-residual (O2).
// ---------------------------------------------------------------------------
#define GEMM_CORE(XPTR, WPTR)                                                  \
  __shared__ _Float16 sA[128 * 40];                                            \
  __shared__ _Float16 sB[64 * 40];                                             \
  const int t = threadIdx.x;                                                   \
  const int bn = blockIdx.x, bm = blockIdx.y;                                  \
  const int lane = t & 63, wv = t >> 6, quad = lane >> 4, l16 = lane & 15;     \
  const int rA = t >> 1, cA = (t & 1) * 16;                                    \
  const int rB = t >> 2, cB = (t & 3) * 8;                                     \
  floatx4 acc[2][4] = {};                                                      \
  const float* ap = XPTR + (size_t)(bm * 128 + rA) * 1024 + cA;                \
  const float* bp = WPTR + (size_t)(bn * 64 + rB) * 1024 + cB;                 \
  for (int kt = 0; kt < 32; kt++) {                                            \
    const float4 a0 = *(const float4*)(ap + kt * 32);                          \
    const float4 a1 = *(const float4*)(ap + kt * 32 + 4);                      \
    const float4 a2 = *(const float4*)(ap + kt * 32 + 8);                      \
    const float4 a3 = *(const float4*)(ap + kt * 32 + 12);                     \
    const float4 b0 = *(const float4*)(bp + kt * 32);                          \
    const float4 b1 = *(const float4*)(bp + kt * 32 + 4);                      \
    const half8 hA0 = cvt8(a0, a1), hA1 = cvt8(a2, a3), hB = cvt8(b0, b1);     \
    __syncthreads();                                                           \
    *(half8*)&sA[rA * 40 + cA] = hA0;                                          \
    *(half8*)&sA[rA * 40 + cA + 8] = hA1;                                      \
    *(half8*)&sB[rB * 40 + cB] = hB;                                           \
    __syncthreads();                                                           \
    half8 af[2], bf[4];                                                        \
    _Pragma("unroll")                                                          \
    for (int mt = 0; mt < 2; mt++)                                             \
      af[mt] = *(const half8*)&sA[(wv * 32 + mt * 16 + l16) * 40 + quad * 8];  \
    _Pragma("unroll")                                                          \
    for (int nt = 0; nt < 4; nt++)                                             \
      bf[nt] = *(const half8*)&sB[(nt * 16 + l16) * 40 + quad * 8];            \
    _Pragma("unroll")                                                          \
    for (int mt = 0; mt < 2; mt++)                                             \
      _Pragma("unroll")                                                        \
      for (int nt = 0; nt < 4; nt++)                                           \
        acc[mt][nt] = __builtin_amdgcn_mfma_f32_16x16x32_f16(af[mt], bf[nt],   \
                                                             acc[mt][nt], 0, 0, 0); \
  }

__global__ __launch_bounds__(256) void gemm_proj_f32(
    const float* __restrict__ X, const float* __restrict__ W,
    const int* __restrict__ mask, float* __restrict__ out)
{
  GEMM_CORE(X, W)
#pragma unroll
  for (int mt = 0; mt < 2; mt++)
#pragma unroll
    for (int rr = 0; rr < 4; rr++) {
      const int row = bm * 128 + wv * 32 + mt * 16 + quad * 4 + rr;
      const int msk = mask[row];
#pragma unroll
      for (int nt = 0; nt < 4; nt++)
        out[(size_t)row * 1024 + bn * 64 + nt * 16 + l16] = msk ? 0.0f : acc[mt][nt][rr];
    }
}

__global__ __launch_bounds__(256) void gemm_proj_f16(
    const float* __restrict__ X, const float* __restrict__ W,
    const int* __restrict__ mask, _Float16* __restrict__ out)
{
  GEMM_CORE(X, W)
#pragma unroll
  for (int mt = 0; mt < 2; mt++)
#pragma unroll
    for (int rr = 0; rr < 4; rr++) {
      const int row = bm * 128 + wv * 32 + mt * 16 + quad * 4 + rr;
      const int msk = mask[row];
#pragma unroll
      for (int nt = 0; nt < 4; nt++)
        out[(size_t)row * 1024 + bn * 64 + nt * 16 + l16] =
            msk ? (_Float16)0.0f : (_Float16)acc[mt][nt][rr];
    }
}

__global__ __launch_bounds__(256) void gemm_wo(
    const float* __restrict__ X1, const float* __restrict__ W,
    float* __restrict__ O2)
{
  GEMM_CORE(X1, W)
#pragma unroll
  for (int mt = 0; mt < 2; mt++)
#pragma unroll
    for (int rr = 0; rr < 4; rr++) {
      const int row = bm * 128 + wv * 32 + mt * 16 + quad * 4 + rr;
#pragma unroll
      for (int nt = 0; nt < 4; nt++) {
        const size_t idx = (size_t)row * 1024 + bn * 64 + nt * 16 + l16;
        const float hv = acc[mt][nt][rr];
        const float ge = 0.5f * hv * (1.0f + erff(hv * 0.70710678118654752f));
        O2[idx] = X1[idx] + ge;   // masked rows: X1=0 -> 0 (matches ref)
      }
    }
}

// ---------------------------------------------------------------------------
// V transpose: Vh[b,k,h*64+d] f16 -> Vt[(b*16+h)*64+d][k] f16, via 64x64 LDS
// tile per (kt, bh). Both global sides coalesced; transposed side lives in LDS.
// ---------------------------------------------------------------------------
__global__ __launch_bounds__(256) void v_transpose(
    const _Float16* __restrict__ Vh, _Float16* __restrict__ Vt)
{
  __shared__ _Float16 sT[64 * AST];
  const int t = threadIdx.x;
  const int kt = blockIdx.x, bh = blockIdx.y;
  const int b = bh >> 4, h = bh & 15;
  const int r = t >> 2, c0 = (t & 3) * 16;
  const _Float16* src = Vh + (size_t)(b * 1024 + kt * 64 + r) * 1024 + h * 64 + c0;
  *(half8*)&sT[r * AST + c0] = *(const half8*)src;
  *(half8*)&sT[r * AST + c0 + 8] = *(const half8*)(src + 8);
  __syncthreads();
  half8 o0, o1;
#pragma unroll
  for (int j = 0; j < 8; j++) o0[j] = sT[(c0 + j) * AST + r];
#pragma unroll
  for (int j = 0; j < 8; j++) o1[j] = sT[(c0 + 8 + j) * AST + r];
  _Float16* dst = Vt + ((size_t)bh * 64 + r) * 1024 + kt * 64 + c0;
  *(half8*)dst = o0;
  *(half8*)(dst + 8) = o1;
}

// ---------------------------------------------------------------------------
// MFMA flash attention v2: f16 K (row-major) + f16 V^T (pre-transposed) ->
// staging is pure vector copy (no cvt, no in-kernel transpose, no b16 scatter).
// Block = 64 q-rows of one (b,h); 4 waves x 16 rows; online softmax; P via
// wave-private LDS round-trip. Epilogue: O1 = maskQ ? 0 : Qp + O/l.
// ---------------------------------------------------------------------------
__global__ __launch_bounds__(256) void attn_mfma2(
    const float* __restrict__ Qp, const _Float16* __restrict__ Kh,
    const _Float16* __restrict__ Vt, const int* __restrict__ maskQ,
    const int* __restrict__ maskK, float* __restrict__ O1)
{
  __shared__ _Float16 sK[64 * AST];
  __shared__ _Float16 sV[64 * AST];
  __shared__ _Float16 sQP[64 * AST];
  __shared__ float bias[1024];

  const int t = threadIdx.x;
  const int qt = blockIdx.x, bh = blockIdx.y;
  const int b = bh >> 4, h = bh & 15;
  const int q0 = qt * 64;
  const size_t base = (size_t)b * 1024;
  const int wv = t >> 6, lane = t & 63, quad = lane >> 4, l16 = lane & 15;
  const int r = t >> 2, c0 = (t & 3) * 16;

  for (int i = t; i < 1024; i += 256)
    bias[i] = maskK[b * 1024 + i] ? -1e30f : 0.0f;

  {  // stage Q tile (64x64 fp32 -> f16), once
    const float* qp = Qp + (base + q0 + r) * 1024 + h * 64 + c0;
    const float4 v0 = *(const float4*)(qp);
    const float4 v1 = *(const float4*)(qp + 4);
    const float4 v2 = *(const float4*)(qp + 8);
    const float4 v3 = *(const float4*)(qp + 12);
    *(half8*)&sQP[r * AST + c0] = cvt8(v0, v1);
    *(half8*)&sQP[r * AST + c0 + 8] = cvt8(v2, v3);
  }
  __syncthreads();

  const half8 aq0 = *(const half8*)&sQP[(wv * 16 + l16) * AST + quad * 8];
  const half8 aq1 = *(const half8*)&sQP[(wv * 16 + l16) * AST + 32 + quad * 8];

  float m_i[4], l_i[4];
  floatx4 acc_o[4] = {};
#pragma unroll
  for (int i = 0; i < 4; i++) { m_i[i] = -1e30f; l_i[i] = 0.0f; }

  for (int kt = 0; kt < 16; kt++) {
    __syncthreads();                 // prev iter's frag reads done
    {
      const _Float16* kp = Kh + (base + kt * 64 + r) * 1024 + h * 64 + c0;
      const _Float16* vp = Vt + ((size_t)bh * 64 + r) * 1024 + kt * 64 + c0;
      const half8 k0v = *(const half8*)kp;
      const half8 k1v = *(const half8*)(kp + 8);
      const half8 v0v = *(const half8*)vp;
      const half8 v1v = *(const half8*)(vp + 8);
      *(half8*)&sK[r * AST + c0] = k0v;
      *(half8*)&sK[r * AST + c0 + 8] = k1v;
      *(half8*)&sV[r * AST + c0] = v0v;
      *(half8*)&sV[r * AST + c0 + 8] = v1v;
    }
    __syncthreads();

    // S = Q.K^T (wave: 16q x 64k), scale + mask-bias
    floatx4 s[4] = {};
#pragma unroll
    for (int nt = 0; nt < 4; nt++) {
      const half8 bk0 = *(const half8*)&sK[(nt * 16 + l16) * AST + quad * 8];
      const half8 bk1 = *(const half8*)&sK[(nt * 16 + l16) * AST + 32 + quad * 8];
      s[nt] = __builtin_amdgcn_mfma_f32_16x16x32_f16(aq0, bk0, s[nt], 0, 0, 0);
      s[nt] = __builtin_amdgcn_mfma_f32_16x16x32_f16(aq1, bk1, s[nt], 0, 0, 0);
    }
#pragma unroll
    for (int nt = 0; nt < 4; nt++) {
      const float bv = bias[kt * 64 + nt * 16 + l16];
#pragma unroll
      for (int rr = 0; rr < 4; rr++)
        s[nt][rr] = s[nt][rr] * 0.03125f + bv;   // /sqrt(1024)
    }

    // online softmax (rows = quad*4+rr; cols over 16 lanes x 4 nt)
    float mn[4], alpha[4], rsum[4];
#pragma unroll
    for (int rr = 0; rr < 4; rr++) {
      float mx = fmaxf(fmaxf(s[0][rr], s[1][rr]), fmaxf(s[2][rr], s[3][rr]));
#pragma unroll
      for (int off = 8; off >= 1; off >>= 1) mx = fmaxf(mx, __shfl_xor(mx, off));
      mn[rr] = fmaxf(m_i[rr], mx);
      alpha[rr] = __expf(m_i[rr] - mn[rr]);
      m_i[rr] = mn[rr];
      rsum[rr] = 0.0f;
    }
#pragma unroll
    for (int nt = 0; nt < 4; nt++)
#pragma unroll
      for (int rr = 0; rr < 4; rr++) {
        const float sv = s[nt][rr];
        const float p = (sv <= -1e20f) ? 0.0f : __expf(sv - mn[rr]);
        s[nt][rr] = p;
        rsum[rr] += p;
      }
#pragma unroll
    for (int rr = 0; rr < 4; rr++) {
#pragma unroll
      for (int off = 8; off >= 1; off >>= 1) rsum[rr] += __shfl_xor(rsum[rr], off);
      l_i[rr] = l_i[rr] * alpha[rr] + rsum[rr];
    }
#pragma unroll
    for (int nt = 0; nt < 4; nt++)
#pragma unroll
      for (int rr = 0; rr < 4; rr++)
        acc_o[nt][rr] *= alpha[rr];

    // P: C-layout -> wave-private LDS rows -> A-layout frags (same-wave DS order)
#pragma unroll
    for (int nt = 0; nt < 4; nt++)
#pragma unroll
      for (int rr = 0; rr < 4; rr++)
        sQP[(wv * 16 + quad * 4 + rr) * AST + nt * 16 + l16] = (_Float16)s[nt][rr];

    const half8 ap0 = *(const half8*)&sQP[(wv * 16 + l16) * AST + quad * 8];
    const half8 ap1 = *(const half8*)&sQP[(wv * 16 + l16) * AST + 32 + quad * 8];
#pragma unroll
    for (int nt = 0; nt < 4; nt++) {
      const half8 bv0 = *(const half8*)&sV[(nt * 16 + l16) * AST + quad * 8];
      const half8 bv1 = *(const half8*)&sV[(nt * 16 + l16) * AST + 32 + quad * 8];
      acc_o[nt] = __builtin_amdgcn_mfma_f32_16x16x32_f16(ap0, bv0, acc_o[nt], 0, 0, 0);
      acc_o[nt] = __builtin_amdgcn_mfma_f32_16x16x32_f16(ap1, bv1, acc_o[nt], 0, 0, 0);
    }
  }

  // epilogue: O1 = maskQ ? 0 : Qp + O/l
#pragma unroll
  for (int rr = 0; rr < 4; rr++) {
    const int row = q0 + wv * 16 + quad * 4 + rr;
    const float inv = (l_i[rr] > 0.0f) ? 1.0f / l_i[rr] : 0.0f;
    const int mq = maskQ[b * 1024 + row];
#pragma unroll
    for (int nt = 0; nt < 4; nt++) {
      const size_t gi = (base + row) * 1024 + h * 64 + nt * 16 + l16;
      O1[gi] = mq ? 0.0f : (Qp[gi] + acc_o[nt][rr] * inv);
    }
  }
}

// ---------------------------------------------------------------------------
// LayerNorm (one row of 1024 per block), fp32 in/out.
// ---------------------------------------------------------------------------
__device__ __forceinline__ void ln_stats(float4 x, int t, float* mean, float* rinv) {
  float s = x.x + x.y + x.z + x.w;
  float s2 = x.x * x.x + x.y * x.y + x.z * x.z + x.w * x.w;
#pragma unroll
  for (int off = 32; off >= 1; off >>= 1) { s += __shfl_xor(s, off); s2 += __shfl_xor(s2, off); }
  __shared__ float red[8];
  __shared__ float sm[2];
  const int wv = t >> 6, lane = t & 63;
  if (lane == 0) { red[wv] = s; red[4 + wv] = s2; }
  __syncthreads();
  if (t == 0) {
    const float S = red[0] + red[1] + red[2] + red[3];
    const float S2 = red[4] + red[5] + red[6] + red[7];
    const float m = S * (1.0f / 1024.0f);
    const float v = S2 * (1.0f / 1024.0f) - m * m;
    sm[0] = m; sm[1] = rsqrtf(v + 1e-5f);
  }
  __syncthreads();
  *mean = sm[0]; *rinv = sm[1];
}

__global__ __launch_bounds__(256) void ln_f32(
    const float* __restrict__ X, const float* __restrict__ g,
    const float* __restrict__ bta, const int* __restrict__ mask,
    float* __restrict__ out)
{
  const int rr = blockIdx.x, t = threadIdx.x, c = 4 * t;
  const float4 x = *(const float4*)&X[(size_t)rr * 1024 + c];
  float mean, ri;
  ln_stats(x, t, &mean, &ri);
  const int msk = mask[rr];
  const float4 gg = *(const float4*)&g[c];
  const float4 bb = *(const float4*)&bta[c];
  float4 o;
  o.x = msk ? 0.f : (x.x - mean) * ri * gg.x + bb.x;
  o.y = msk ? 0.f : (x.y - mean) * ri * gg.y + bb.y;
  o.z = msk ? 0.f : (x.z - mean) * ri * gg.z + bb.z;
  o.w = msk ? 0.f : (x.w - mean) * ri * gg.w + bb.w;
  *(float4*)&out[(size_t)rr * 1024 + c] = o;
}

// ---------------------------------------------------------------------------
extern "C" void kernel_launch(void* const* d_in, const int* in_sizes, int n_in,
                              void* d_out, int out_size, void* d_ws, size_t ws_size,
                              hipStream_t stream)
{
  const float* Q  = (const float*)d_in[0];
  const float* K  = (const float*)d_in[1];
  const float* V  = (const float*)d_in[2];
  const float* Wq = (const float*)d_in[3];
  const float* Wk = (const float*)d_in[4];
  const float* Wv = (const float*)d_in[5];
  const float* Wo = (const float*)d_in[6];
  const float* g1 = (const float*)d_in[7];
  const float* b1 = (const float*)d_in[8];
  const float* g2 = (const float*)d_in[9];
  const float* b2 = (const float*)d_in[10];
  float* out = (float*)d_out;

  char* base = (char*)d_ws;
  const size_t MB_ = 1024 * 1024;
  float*     Qp = (float*)base;                     // [0, 16) MB
  _Float16*  Kh = (_Float16*)(base + 16 * MB_);     // [16, 24) MB
  _Float16*  Vh = (_Float16*)(base + 24 * MB_);     // [24, 32) MB
  _Float16*  Vt = (_Float16*)(base + 32 * MB_);     // [32, 40) MB
  float*     O1 = (float*)(base + 40 * MB_);        // [40, 56) MB
  float*     X1 = (float*)(base + 16 * MB_);        // reuse Kh∪Vh after attn
  float*     O2 = Qp;                               // reuse Qp after attn
  int*       mQ = (int*)(base + 56 * MB_);
  int*       mK = mQ + NTOK;                        // peak: 56 MB + 32 KB

  const dim3 bb(256);
  const dim3 gG(16, 32);   // GEMM: 16 n-tiles x 32 m-tiles
  mask_prep<<<dim3(16), bb, 0, stream>>>((const int*)d_in[11], (const int*)d_in[12], mQ, mK);
  gemm_proj_f32<<<gG, bb, 0, stream>>>(Q, Wq, mQ, Qp);
  gemm_proj_f16<<<gG, bb, 0, stream>>>(K, Wk, mK, Kh);
  gemm_proj_f16<<<gG, bb, 0, stream>>>(V, Wv, mK, Vh);
  v_transpose<<<dim3(16, 64), bb, 0, stream>>>(Vh, Vt);
  attn_mfma2<<<dim3(16, 64), bb, 0, stream>>>(Qp, Kh, Vt, mQ, mK, O1);
  ln_f32<<<dim3(4096), bb, 0, stream>>>(O1, g1, b1, mQ, X1);
  gemm_wo<<<gG, bb, 0, stream>>>(X1, Wo, O2);
  ln_f32<<<dim3(4096), bb, 0, stream>>>(O2, g2, b2, mQ, out);
}

// Round 8
// 330.487 us; speedup vs baseline: 1.0774x; 1.0774x over previous
//
#include <hip/hip_runtime.h>

// Problem constants (B=4, N=1024, DIM=1024, H=16, DH=64)
// Dtype model (r5-proven): tensor inputs fp32, masks int32, d_out fp32.
#define NTOK 4096
#define AST 72   // attn LDS row stride in halves

typedef _Float16 half4v __attribute__((ext_vector_type(4)));
typedef _Float16 half8 __attribute__((ext_vector_type(8)));
typedef float floatx4 __attribute__((ext_vector_type(4)));

__device__ __forceinline__ half8 cvt8(float4 a, float4 b) {
  half8 h;
  h[0] = (_Float16)a.x; h[1] = (_Float16)a.y; h[2] = (_Float16)a.z; h[3] = (_Float16)a.w;
  h[4] = (_Float16)b.x; h[5] = (_Float16)b.y; h[6] = (_Float16)b.z; h[7] = (_Float16)b.w;
  return h;
}

#if defined(__has_builtin)
#if __has_builtin(__builtin_amdgcn_global_load_lds)
#define HAS_GLL 1
#endif
#endif

// Stage 64 lanes x 16 B: global (per-lane addr) -> LDS (wave-uniform base + lane*16).
#ifdef HAS_GLL
#define STAGE16(gp, lp)                                                        \
  __builtin_amdgcn_global_load_lds(                                           \
      (const __attribute__((address_space(1))) void*)(gp),                     \
      (__attribute__((address_space(3))) void*)(lp), 16, 0, 0)
#else
#define STAGE16(gp, lp)                                                        \
  do { *(half8*)((_Float16*)(lp) + lane * 8) = *(const half8*)(gp); } while (0)
#endif

// ---------------------------------------------------------------------------
// Mask canonicalization (r3 proved masks arrive int32; kept for robustness).
// ---------------------------------------------------------------------------
__device__ __forceinline__ int mask_is_bytes(const int* p) {
  int bad = 0;
#pragma unroll
  for (int i = 0; i < 64; i++) bad |= (((unsigned int)p[i]) > 1u);
  return bad;
}

__global__ __launch_bounds__(256) void mask_prep(
    const int* __restrict__ srcQ, const int* __restrict__ srcK,
    int* __restrict__ dstQ, int* __restrict__ dstK)
{
  const int t = blockIdx.x * 256 + threadIdx.x;
  const int bq = mask_is_bytes(srcQ);
  const int bk = mask_is_bytes(srcK);
  dstQ[t] = bq ? (int)((const unsigned char*)srcQ)[t] : srcQ[t];
  dstK[t] = bk ? (int)((const unsigned char*)srcK)[t] : srcK[t];
}

// ---------------------------------------------------------------------------
// One-shot fp32 -> f16 conversion of all GEMM operands (Q,K,V inputs + weights).
// 8192 blocks x 256 thr x 8 elems.
// ---------------------------------------------------------------------------
__global__ __launch_bounds__(256) void cvt_all(
    const float* __restrict__ Q, const float* __restrict__ K, const float* __restrict__ V,
    const float* __restrict__ Wq, const float* __restrict__ Wk, const float* __restrict__ Wv,
    const float* __restrict__ Wo,
    _Float16* __restrict__ Xq, _Float16* __restrict__ Xk, _Float16* __restrict__ Xv,
    _Float16* __restrict__ Wqh, _Float16* __restrict__ Wkh, _Float16* __restrict__ Wvh,
    _Float16* __restrict__ Woh)
{
  const int blk = blockIdx.x;
  const float* src; _Float16* dst; size_t off;
  if      (blk < 2048) { src = Q;  dst = Xq;  off = (size_t)blk * 2048; }
  else if (blk < 4096) { src = K;  dst = Xk;  off = (size_t)(blk - 2048) * 2048; }
  else if (blk < 6144) { src = V;  dst = Xv;  off = (size_t)(blk - 4096) * 2048; }
  else if (blk < 6656) { src = Wq; dst = Wqh; off = (size_t)(blk - 6144) * 2048; }
  else if (blk < 7168) { src = Wk; dst = Wkh; off = (size_t)(blk - 6656) * 2048; }
  else if (blk < 7680) { src = Wv; dst = Wvh; off = (size_t)(blk - 7168) * 2048; }
  else                 { src = Wo; dst = Woh; off = (size_t)(blk - 7680) * 2048; }
  const size_t i = off + (size_t)threadIdx.x * 8;
  const float4 a = *(const float4*)(src + i);
  const float4 b = *(const float4*)(src + i + 4);
  *(half8*)(dst + i) = cvt8(a, b);
}

// ---------------------------------------------------------------------------
// m97-style f16 GEMM: out[m,n] = sum_k A[m,k]*B[n,k], A/B f16, K=1024.
// 128x128 tile, BK=32, 4 waves (2x2), 16 MFMA + 8 ds_read_b128 per wave-iter,
// staging via global_load_lds width=16 into unpadded LDS (rows of 32 halves).
// Wave w stages rows [w*32, w*32+32) of both tiles (2 instrs each of A and B).
// Frags: A[m=l16][k=quad*8+j]; C/D: row=quad*4+reg, col=l16 (r2/r4-verified).
// ---------------------------------------------------------------------------
#define GEMM97_CORE(AH, BH)                                                    \
  __shared__ _Float16 sA[128 * 32];                                            \
  __shared__ _Float16 sB[128 * 32];                                            \
  const int t = threadIdx.x;                                                   \
  const int bn = blockIdx.x, bm = blockIdx.y;                                  \
  const int lane = t & 63, wv = t >> 6, quad = lane >> 4, l16 = lane & 15;     \
  const int wm = wv & 1, wn = wv >> 1;                                         \
  const int srow = wv * 32 + (lane >> 2);                                      \
  const int scol = (lane & 3) * 8;                                             \
  floatx4 acc[4][4] = {};                                                      \
  const _Float16* gA = AH + (size_t)(bm * 128 + srow) * 1024 + scol;           \
  const _Float16* gB = BH + (size_t)(bn * 128 + srow) * 1024 + scol;           \
  for (int kt = 0; kt < 32; kt++) {                                            \
    __syncthreads();                                                           \
    STAGE16(gA + kt * 32,         &sA[(wv * 32) * 32]);                        \
    STAGE16(gA + kt * 32 + 16384, &sA[(wv * 32 + 16) * 32]);                   \
    STAGE16(gB + kt * 32,         &sB[(wv * 32) * 32]);                        \
    STAGE16(gB + kt * 32 + 16384, &sB[(wv * 32 + 16) * 32]);                   \
    __syncthreads();                                                           \
    half8 af[4], bf[4];                                                        \
    _Pragma("unroll")                                                          \
    for (int s = 0; s < 4; s++)                                                \
      af[s] = *(const half8*)&sA[(wm * 64 + s * 16 + l16) * 32 + quad * 8];    \
    _Pragma("unroll")                                                          \
    for (int u = 0; u < 4; u++)                                                \
      bf[u] = *(const half8*)&sB[(wn * 64 + u * 16 + l16) * 32 + quad * 8];    \
    _Pragma("unroll")                                                          \
    for (int s = 0; s < 4; s++)                                                \
      _Pragma("unroll")                                                        \
      for (int u = 0; u < 4; u++)                                              \
        acc[s][u] = __builtin_amdgcn_mfma_f32_16x16x32_f16(af[s], bf[u],       \
                                                           acc[s][u], 0, 0, 0); \
  }

__global__ __launch_bounds__(256) void gemm_a16_f32(
    const _Float16* __restrict__ AH, const _Float16* __restrict__ BH,
    const int* __restrict__ mask, float* __restrict__ out)
{
  GEMM97_CORE(AH, BH)
#pragma unroll
  for (int s = 0; s < 4; s++)
#pragma unroll
    for (int rr = 0; rr < 4; rr++) {
      const int row = bm * 128 + wm * 64 + s * 16 + quad * 4 + rr;
      const int msk = mask[row];
#pragma unroll
      for (int u = 0; u < 4; u++)
        out[(size_t)row * 1024 + bn * 128 + wn * 64 + u * 16 + l16] =
            msk ? 0.0f : acc[s][u][rr];
    }
}

__global__ __launch_bounds__(256) void gemm_a16_f16(
    const _Float16* __restrict__ AH, const _Float16* __restrict__ BH,
    const int* __restrict__ mask, _Float16* __restrict__ out)
{
  GEMM97_CORE(AH, BH)
#pragma unroll
  for (int s = 0; s < 4; s++)
#pragma unroll
    for (int rr = 0; rr < 4; rr++) {
      const int row = bm * 128 + wm * 64 + s * 16 + quad * 4 + rr;
      const int msk = mask[row];
#pragma unroll
      for (int u = 0; u < 4; u++)
        out[(size_t)row * 1024 + bn * 128 + wn * 64 + u * 16 + l16] =
            msk ? (_Float16)0.0f : (_Float16)acc[s][u][rr];
    }
}

__global__ __launch_bounds__(256) void gemm_a16_wo(
    const _Float16* __restrict__ AH, const _Float16* __restrict__ BH,
    const float* __restrict__ X1, float* __restrict__ O2)
{
  GEMM97_CORE(AH, BH)
#pragma unroll
  for (int s = 0; s < 4; s++)
#pragma unroll
    for (int rr = 0; rr < 4; rr++) {
      const int row = bm * 128 + wm * 64 + s * 16 + quad * 4 + rr;
#pragma unroll
      for (int u = 0; u < 4; u++) {
        const size_t idx = (size_t)row * 1024 + bn * 128 + wn * 64 + u * 16 + l16;
        const float hv = acc[s][u][rr];
        const float ge = 0.5f * hv * (1.0f + erff(hv * 0.70710678118654752f));
        O2[idx] = X1[idx] + ge;   // masked rows: X1=0 -> 0 (matches ref)
      }
    }
}

// ---------------------------------------------------------------------------
// V transpose: Vh[b,k,h*64+d] f16 -> Vt[(b*16+h)*64+d][k] f16 (64x64 LDS tile).
// ---------------------------------------------------------------------------
__global__ __launch_bounds__(256) void v_transpose(
    const _Float16* __restrict__ Vh, _Float16* __restrict__ Vt)
{
  __shared__ _Float16 sT[64 * AST];
  const int t = threadIdx.x;
  const int kt = blockIdx.x, bh = blockIdx.y;
  const int b = bh >> 4, h = bh & 15;
  const int r = t >> 2, c0 = (t & 3) * 16;
  const _Float16* src = Vh + (size_t)(b * 1024 + kt * 64 + r) * 1024 + h * 64 + c0;
  *(half8*)&sT[r * AST + c0] = *(const half8*)src;
  *(half8*)&sT[r * AST + c0 + 8] = *(const half8*)(src + 8);
  __syncthreads();
  half8 o0, o1;
#pragma unroll
  for (int j = 0; j < 8; j++) o0[j] = sT[(c0 + j) * AST + r];
#pragma unroll
  for (int j = 0; j < 8; j++) o1[j] = sT[(c0 + 8 + j) * AST + r];
  _Float16* dst = Vt + ((size_t)bh * 64 + r) * 1024 + kt * 64 + c0;
  *(half8*)dst = o0;
  *(half8*)(dst + 8) = o1;
}

// ---------------------------------------------------------------------------
// MFMA flash attention (r7, unchanged): f16 K + f16 V^T, 64 q-rows/block.
// ---------------------------------------------------------------------------
__global__ __launch_bounds__(256) void attn_mfma2(
    const float* __restrict__ Qp, const _Float16* __restrict__ Kh,
    const _Float16* __restrict__ Vt, const int* __restrict__ maskQ,
    const int* __restrict__ maskK, float* __restrict__ O1)
{
  __shared__ _Float16 sK[64 * AST];
  __shared__ _Float16 sV[64 * AST];
  __shared__ _Float16 sQP[64 * AST];
  __shared__ float bias[1024];

  const int t = threadIdx.x;
  const int qt = blockIdx.x, bh = blockIdx.y;
  const int b = bh >> 4, h = bh & 15;
  const int q0 = qt * 64;
  const size_t base = (size_t)b * 1024;
  const int wv = t >> 6, lane = t & 63, quad = lane >> 4, l16 = lane & 15;
  const int r = t >> 2, c0 = (t & 3) * 16;

  for (int i = t; i < 1024; i += 256)
    bias[i] = maskK[b * 1024 + i] ? -1e30f : 0.0f;

  {
    const float* qp = Qp + (base + q0 + r) * 1024 + h * 64 + c0;
    const float4 v0 = *(const float4*)(qp);
    const float4 v1 = *(const float4*)(qp + 4);
    const float4 v2 = *(const float4*)(qp + 8);
    const float4 v3 = *(const float4*)(qp + 12);
    *(half8*)&sQP[r * AST + c0] = cvt8(v0, v1);
    *(half8*)&sQP[r * AST + c0 + 8] = cvt8(v2, v3);
  }
  __syncthreads();

  const half8 aq0 = *(const half8*)&sQP[(wv * 16 + l16) * AST + quad * 8];
  const half8 aq1 = *(const half8*)&sQP[(wv * 16 + l16) * AST + 32 + quad * 8];

  float m_i[4], l_i[4];
  floatx4 acc_o[4] = {};
#pragma unroll
  for (int i = 0; i < 4; i++) { m_i[i] = -1e30f; l_i[i] = 0.0f; }

  for (int kt = 0; kt < 16; kt++) {
    __syncthreads();
    {
      const _Float16* kp = Kh + (base + kt * 64 + r) * 1024 + h * 64 + c0;
      const _Float16* vp = Vt + ((size_t)bh * 64 + r) * 1024 + kt * 64 + c0;
      const half8 k0v = *(const half8*)kp;
      const half8 k1v = *(const half8*)(kp + 8);
      const half8 v0v = *(const half8*)vp;
      const half8 v1v = *(const half8*)(vp + 8);
      *(half8*)&sK[r * AST + c0] = k0v;
      *(half8*)&sK[r * AST + c0 + 8] = k1v;
      *(half8*)&sV[r * AST + c0] = v0v;
      *(half8*)&sV[r * AST + c0 + 8] = v1v;
    }
    __syncthreads();

    floatx4 s[4] = {};
#pragma unroll
    for (int nt = 0; nt < 4; nt++) {
      const half8 bk0 = *(const half8*)&sK[(nt * 16 + l16) * AST + quad * 8];
      const half8 bk1 = *(const half8*)&sK[(nt * 16 + l16) * AST + 32 + quad * 8];
      s[nt] = __builtin_amdgcn_mfma_f32_16x16x32_f16(aq0, bk0, s[nt], 0, 0, 0);
      s[nt] = __builtin_amdgcn_mfma_f32_16x16x32_f16(aq1, bk1, s[nt], 0, 0, 0);
    }
#pragma unroll
    for (int nt = 0; nt < 4; nt++) {
      const float bv = bias[kt * 64 + nt * 16 + l16];
#pragma unroll
      for (int rr = 0; rr < 4; rr++)
        s[nt][rr] = s[nt][rr] * 0.03125f + bv;
    }

    float mn[4], alpha[4], rsum[4];
#pragma unroll
    for (int rr = 0; rr < 4; rr++) {
      float mx = fmaxf(fmaxf(s[0][rr], s[1][rr]), fmaxf(s[2][rr], s[3][rr]));
#pragma unroll
      for (int off = 8; off >= 1; off >>= 1) mx = fmaxf(mx, __shfl_xor(mx, off));
      mn[rr] = fmaxf(m_i[rr], mx);
      alpha[rr] = __expf(m_i[rr] - mn[rr]);
      m_i[rr] = mn[rr];
      rsum[rr] = 0.0f;
    }
#pragma unroll
    for (int nt = 0; nt < 4; nt++)
#pragma unroll
      for (int rr = 0; rr < 4; rr++) {
        const float sv = s[nt][rr];
        const float p = (sv <= -1e20f) ? 0.0f : __expf(sv - mn[rr]);
        s[nt][rr] = p;
        rsum[rr] += p;
      }
#pragma unroll
    for (int rr = 0; rr < 4; rr++) {
#pragma unroll
      for (int off = 8; off >= 1; off >>= 1) rsum[rr] += __shfl_xor(rsum[rr], off);
      l_i[rr] = l_i[rr] * alpha[rr] + rsum[rr];
    }
#pragma unroll
    for (int nt = 0; nt < 4; nt++)
#pragma unroll
      for (int rr = 0; rr < 4; rr++)
        acc_o[nt][rr] *= alpha[rr];

#pragma unroll
    for (int nt = 0; nt < 4; nt++)
#pragma unroll
      for (int rr = 0; rr < 4; rr++)
        sQP[(wv * 16 + quad * 4 + rr) * AST + nt * 16 + l16] = (_Float16)s[nt][rr];

    const half8 ap0 = *(const half8*)&sQP[(wv * 16 + l16) * AST + quad * 8];
    const half8 ap1 = *(const half8*)&sQP[(wv * 16 + l16) * AST + 32 + quad * 8];
#pragma unroll
    for (int nt = 0; nt < 4; nt++) {
      const half8 bv0 = *(const half8*)&sV[(nt * 16 + l16) * AST + quad * 8];
      const half8 bv1 = *(const half8*)&sV[(nt * 16 + l16) * AST + 32 + quad * 8];
      acc_o[nt] = __builtin_amdgcn_mfma_f32_16x16x32_f16(ap0, bv0, acc_o[nt], 0, 0, 0);
      acc_o[nt] = __builtin_amdgcn_mfma_f32_16x16x32_f16(ap1, bv1, acc_o[nt], 0, 0, 0);
    }
  }

#pragma unroll
  for (int rr = 0; rr < 4; rr++) {
    const int row = q0 + wv * 16 + quad * 4 + rr;
    const float inv = (l_i[rr] > 0.0f) ? 1.0f / l_i[rr] : 0.0f;
    const int mq = maskQ[b * 1024 + row];
#pragma unroll
    for (int nt = 0; nt < 4; nt++) {
      const size_t gi = (base + row) * 1024 + h * 64 + nt * 16 + l16;
      O1[gi] = mq ? 0.0f : (Qp[gi] + acc_o[nt][rr] * inv);
    }
  }
}

// ---------------------------------------------------------------------------
// LayerNorm (one row of 1024 per block), fp32 in; fp32 out (+ optional f16 copy).
// ---------------------------------------------------------------------------
__device__ __forceinline__ void ln_stats(float4 x, int t, float* mean, float* rinv) {
  float s = x.x + x.y + x.z + x.w;
  float s2 = x.x * x.x + x.y * x.y + x.z * x.z + x.w * x.w;
#pragma unroll
  for (int off = 32; off >= 1; off >>= 1) { s += __shfl_xor(s, off); s2 += __shfl_xor(s2, off); }
  __shared__ float red[8];
  __shared__ float sm[2];
  const int wv = t >> 6, lane = t & 63;
  if (lane == 0) { red[wv] = s; red[4 + wv] = s2; }
  __syncthreads();
  if (t == 0) {
    const float S = red[0] + red[1] + red[2] + red[3];
    const float S2 = red[4] + red[5] + red[6] + red[7];
    const float m = S * (1.0f / 1024.0f);
    const float v = S2 * (1.0f / 1024.0f) - m * m;
    sm[0] = m; sm[1] = rsqrtf(v + 1e-5f);
  }
  __syncthreads();
  *mean = sm[0]; *rinv = sm[1];
}

__global__ __launch_bounds__(256) void ln_f32(
    const float* __restrict__ X, const float* __restrict__ g,
    const float* __restrict__ bta, const int* __restrict__ mask,
    float* __restrict__ out)
{
  const int rr = blockIdx.x, t = threadIdx.x, c = 4 * t;
  const float4 x = *(const float4*)&X[(size_t)rr * 1024 + c];
  float mean, ri;
  ln_stats(x, t, &mean, &ri);
  const int msk = mask[rr];
  const float4 gg = *(const float4*)&g[c];
  const float4 bb = *(const float4*)&bta[c];
  float4 o;
  o.x = msk ? 0.f : (x.x - mean) * ri * gg.x + bb.x;
  o.y = msk ? 0.f : (x.y - mean) * ri * gg.y + bb.y;
  o.z = msk ? 0.f : (x.z - mean) * ri * gg.z + bb.z;
  o.w = msk ? 0.f : (x.w - mean) * ri * gg.w + bb.w;
  *(float4*)&out[(size_t)rr * 1024 + c] = o;
}

__global__ __launch_bounds__(256) void ln_f32h(
    const float* __restrict__ X, const float* __restrict__ g,
    const float* __restrict__ bta, const int* __restrict__ mask,
    float* __restrict__ out, _Float16* __restrict__ outh)
{
  const int rr = blockIdx.x, t = threadIdx.x, c = 4 * t;
  const float4 x = *(const float4*)&X[(size_t)rr * 1024 + c];
  float mean, ri;
  ln_stats(x, t, &mean, &ri);
  const int msk = mask[rr];
  const float4 gg = *(const float4*)&g[c];
  const float4 bb = *(const float4*)&bta[c];
  float4 o;
  o.x = msk ? 0.f : (x.x - mean) * ri * gg.x + bb.x;
  o.y = msk ? 0.f : (x.y - mean) * ri * gg.y + bb.y;
  o.z = msk ? 0.f : (x.z - mean) * ri * gg.z + bb.z;
  o.w = msk ? 0.f : (x.w - mean) * ri * gg.w + bb.w;
  const size_t idx = (size_t)rr * 1024 + c;
  *(float4*)&out[idx] = o;
  half4v hh;
  hh[0] = (_Float16)o.x; hh[1] = (_Float16)o.y;
  hh[2] = (_Float16)o.z; hh[3] = (_Float16)o.w;
  *(half4v*)&outh[idx] = hh;
}

// ---------------------------------------------------------------------------
extern "C" void kernel_launch(void* const* d_in, const int* in_sizes, int n_in,
                              void* d_out, int out_size, void* d_ws, size_t ws_size,
                              hipStream_t stream)
{
  const float* Q  = (const float*)d_in[0];
  const float* K  = (const float*)d_in[1];
  const float* V  = (const float*)d_in[2];
  const float* Wq = (const float*)d_in[3];
  const float* Wk = (const float*)d_in[4];
  const float* Wv = (const float*)d_in[5];
  const float* Wo = (const float*)d_in[6];
  const float* g1 = (const float*)d_in[7];
  const float* b1 = (const float*)d_in[8];
  const float* g2 = (const float*)d_in[9];
  const float* b2 = (const float*)d_in[10];
  float* out = (float*)d_out;

  char* base = (char*)d_ws;
  const size_t MB_ = 1024 * 1024;
  float*    Qp  = (float*)base;                     // [0,16) MB  -> O2 after attn
  _Float16* Kh  = (_Float16*)(base + 16 * MB_);     // [16,24) K-projection
  _Float16* Vh  = (_Float16*)(base + 24 * MB_);     // [24,32) V-projection
  _Float16* Xq  = (_Float16*)(base + 32 * MB_);     // [32,40) Q cvt -> Vt -> X1h
  float*    O1  = (float*)(base + 40 * MB_);        // [40,56)
  _Float16* Xk  = (_Float16*)(base + 56 * MB_);     // [56,64)
  _Float16* Xv  = (_Float16*)(base + 64 * MB_);     // [64,72)
  _Float16* Wqh = (_Float16*)(base + 72 * MB_);     // [72,74)
  _Float16* Wkh = (_Float16*)(base + 74 * MB_);     // [74,76)
  _Float16* Wvh = (_Float16*)(base + 76 * MB_);     // [76,78)
  _Float16* Woh = (_Float16*)(base + 78 * MB_);     // [78,80)
  int*      mQ  = (int*)(base + 80 * MB_);
  int*      mK  = mQ + NTOK;                        // peak: 80 MB + 32 KB
  _Float16* Vt  = Xq;                               // Xq dead after Q-GEMM
  float*    X1  = (float*)(base + 16 * MB_);        // Kh∪Vh dead after attn
  _Float16* X1h = Xq;                               // Vt dead after attn
  float*    O2  = Qp;                               // Qp dead after attn

  const dim3 bb(256);
  const dim3 gG(8, 32);   // 128x128 tiles: 8 n-tiles x 32 m-tiles
  mask_prep<<<dim3(16), bb, 0, stream>>>((const int*)d_in[11], (const int*)d_in[12], mQ, mK);
  cvt_all<<<dim3(8192), bb, 0, stream>>>(Q, K, V, Wq, Wk, Wv, Wo,
                                         Xq, Xk, Xv, Wqh, Wkh, Wvh, Woh);
  gemm_a16_f32<<<gG, bb, 0, stream>>>(Xq, Wqh, mQ, Qp);
  gemm_a16_f16<<<gG, bb, 0, stream>>>(Xk, Wkh, mK, Kh);
  gemm_a16_f16<<<gG, bb, 0, stream>>>(Xv, Wvh, mK, Vh);
  v_transpose<<<dim3(16, 64), bb, 0, stream>>>(Vh, Vt);
  attn_mfma2<<<dim3(16, 64), bb, 0, stream>>>(Qp, Kh, Vt, mQ, mK, O1);
  ln_f32h<<<dim3(4096), bb, 0, stream>>>(O1, g1, b1, mQ, X1, X1h);
  gemm_a16_wo<<<gG, bb, 0, stream>>>(X1h, Woh, X1, O2);
  ln_f32<<<dim3(4096), bb, 0, stream>>>(O2, g2, b2, mQ, out);
}

// Round 9
// 260.994 us; speedup vs baseline: 1.3643x; 1.2663x over previous
//
#include <hip/hip_runtime.h>

// Problem constants (B=4, N=1024, DIM=1024, H=16, DH=64)
// Dtype model (r5-proven): tensor inputs fp32, masks int32, d_out fp32.
#define NTOK 4096
#define AST 72   // attn LDS row stride in halves (144 B: 16B-aligned, bank-stride 4)

typedef _Float16 half4v __attribute__((ext_vector_type(4)));
typedef _Float16 half8 __attribute__((ext_vector_type(8)));
typedef float floatx4 __attribute__((ext_vector_type(4)));

__device__ __forceinline__ half8 cvt8(float4 a, float4 b) {
  half8 h;
  h[0] = (_Float16)a.x; h[1] = (_Float16)a.y; h[2] = (_Float16)a.z; h[3] = (_Float16)a.w;
  h[4] = (_Float16)b.x; h[5] = (_Float16)b.y; h[6] = (_Float16)b.z; h[7] = (_Float16)b.w;
  return h;
}

#if defined(__has_builtin)
#if __has_builtin(__builtin_amdgcn_global_load_lds)
#define HAS_GLL 1
#endif
#endif

#ifdef HAS_GLL
#define STAGE16(gp, lp)                                                        \
  __builtin_amdgcn_global_load_lds(                                           \
      (const __attribute__((address_space(1))) void*)(gp),                     \
      (__attribute__((address_space(3))) void*)(lp), 16, 0, 0)
#else
#define STAGE16(gp, lp)                                                        \
  do { *(half8*)((_Float16*)(lp) + lane * 8) = *(const half8*)(gp); } while (0)
#endif

// ---------------------------------------------------------------------------
// Mask canonicalization (r3 proved masks arrive int32; kept for robustness).
// ---------------------------------------------------------------------------
__device__ __forceinline__ int mask_is_bytes(const int* p) {
  int bad = 0;
#pragma unroll
  for (int i = 0; i < 64; i++) bad |= (((unsigned int)p[i]) > 1u);
  return bad;
}

__global__ __launch_bounds__(256) void mask_prep(
    const int* __restrict__ srcQ, const int* __restrict__ srcK,
    int* __restrict__ dstQ, int* __restrict__ dstK)
{
  const int t = blockIdx.x * 256 + threadIdx.x;
  const int bq = mask_is_bytes(srcQ);
  const int bk = mask_is_bytes(srcK);
  dstQ[t] = bq ? (int)((const unsigned char*)srcQ)[t] : srcQ[t];
  dstK[t] = bk ? (int)((const unsigned char*)srcK)[t] : srcK[t];
}

// ---------------------------------------------------------------------------
// One-shot fp32 -> f16 conversion of GEMM operands (Q,K,V inputs + 4 weights).
// ---------------------------------------------------------------------------
__global__ __launch_bounds__(256) void cvt_all(
    const float* __restrict__ Q, const float* __restrict__ K, const float* __restrict__ V,
    const float* __restrict__ Wq, const float* __restrict__ Wk, const float* __restrict__ Wv,
    const float* __restrict__ Wo,
    _Float16* __restrict__ Xq, _Float16* __restrict__ Xk, _Float16* __restrict__ Xv,
    _Float16* __restrict__ Wqh, _Float16* __restrict__ Wkh, _Float16* __restrict__ Wvh,
    _Float16* __restrict__ Woh)
{
  const int blk = blockIdx.x;
  const float* src; _Float16* dst; size_t off;
  if      (blk < 2048) { src = Q;  dst = Xq;  off = (size_t)blk * 2048; }
  else if (blk < 4096) { src = K;  dst = Xk;  off = (size_t)(blk - 2048) * 2048; }
  else if (blk < 6144) { src = V;  dst = Xv;  off = (size_t)(blk - 4096) * 2048; }
  else if (blk < 6656) { src = Wq; dst = Wqh; off = (size_t)(blk - 6144) * 2048; }
  else if (blk < 7168) { src = Wk; dst = Wkh; off = (size_t)(blk - 6656) * 2048; }
  else if (blk < 7680) { src = Wv; dst = Wvh; off = (size_t)(blk - 7168) * 2048; }
  else                 { src = Wo; dst = Woh; off = (size_t)(blk - 7680) * 2048; }
  const size_t i = off + (size_t)threadIdx.x * 8;
  const float4 a = *(const float4*)(src + i);
  const float4 b = *(const float4*)(src + i + 4);
  *(half8*)(dst + i) = cvt8(a, b);
}

// ---------------------------------------------------------------------------
// 128x128 m97-style f16 GEMM core (r8-verified). BK=32, 4 waves (2x2).
// ---------------------------------------------------------------------------
#define GEMM97_CORE(AH, BH)                                                    \
  __shared__ _Float16 sA[128 * 32];                                            \
  __shared__ _Float16 sB[128 * 32];                                            \
  const int t = threadIdx.x;                                                   \
  const int bn = blockIdx.x, bm = blockIdx.y;                                  \
  const int lane = t & 63, wv = t >> 6, quad = lane >> 4, l16 = lane & 15;     \
  const int wm = wv & 1, wn = wv >> 1;                                         \
  const int srow = wv * 32 + (lane >> 2);                                      \
  const int scol = (lane & 3) * 8;                                             \
  floatx4 acc[4][4] = {};                                                      \
  const _Float16* gA = AH + (size_t)(bm * 128 + srow) * 1024 + scol;           \
  const _Float16* gB = BH + (size_t)(bn * 128 + srow) * 1024 + scol;           \
  for (int kt = 0; kt < 32; kt++) {                                            \
    __syncthreads();                                                           \
    STAGE16(gA + kt * 32,         &sA[(wv * 32) * 32]);                        \
    STAGE16(gA + kt * 32 + 16384, &sA[(wv * 32 + 16) * 32]);                   \
    STAGE16(gB + kt * 32,         &sB[(wv * 32) * 32]);                        \
    STAGE16(gB + kt * 32 + 16384, &sB[(wv * 32 + 16) * 32]);                   \
    __syncthreads();                                                           \
    half8 af[4], bf[4];                                                        \
    _Pragma("unroll")                                                          \
    for (int s = 0; s < 4; s++)                                                \
      af[s] = *(const half8*)&sA[(wm * 64 + s * 16 + l16) * 32 + quad * 8];    \
    _Pragma("unroll")                                                          \
    for (int u = 0; u < 4; u++)                                                \
      bf[u] = *(const half8*)&sB[(wn * 64 + u * 16 + l16) * 32 + quad * 8];    \
    _Pragma("unroll")                                                          \
    for (int s = 0; s < 4; s++)                                                \
      _Pragma("unroll")                                                        \
      for (int u = 0; u < 4; u++)                                              \
        acc[s][u] = __builtin_amdgcn_mfma_f32_16x16x32_f16(af[s], bf[u],       \
                                                           acc[s][u], 0, 0, 0); \
  }

// Batched QKV projection: blockIdx.z selects (A, W, mask, out). All f16 out.
__global__ __launch_bounds__(256) void qkv_gemm(
    const _Float16* __restrict__ Xq, const _Float16* __restrict__ Xk,
    const _Float16* __restrict__ Xv,
    const _Float16* __restrict__ Wqh, const _Float16* __restrict__ Wkh,
    const _Float16* __restrict__ Wvh,
    const int* __restrict__ mQ, const int* __restrict__ mK,
    _Float16* __restrict__ Qh, _Float16* __restrict__ Kh, _Float16* __restrict__ Vh)
{
  const int z = blockIdx.z;
  const _Float16* AH = (z == 0) ? Xq : (z == 1) ? Xk : Xv;
  const _Float16* BH = (z == 0) ? Wqh : (z == 1) ? Wkh : Wvh;
  const int* msk = (z == 0) ? mQ : mK;
  _Float16* out = (z == 0) ? Qh : (z == 1) ? Kh : Vh;
  GEMM97_CORE(AH, BH)
#pragma unroll
  for (int s = 0; s < 4; s++)
#pragma unroll
    for (int rr = 0; rr < 4; rr++) {
      const int row = bm * 128 + wm * 64 + s * 16 + quad * 4 + rr;
      const int m = msk[row];
#pragma unroll
      for (int u = 0; u < 4; u++)
        out[(size_t)row * 1024 + bn * 128 + wn * 64 + u * 16 + l16] =
            m ? (_Float16)0.0f : (_Float16)acc[s][u][rr];
    }
}

// ---------------------------------------------------------------------------
// 128x64 f16 GEMM (Wo): 512 blocks = 2/CU. 4 waves along M (32 rows each).
// Epilogue: O2 = X1 + gelu_exact(X1 @ Wo^T).
// ---------------------------------------------------------------------------
__global__ __launch_bounds__(256) void gemm_wo(
    const _Float16* __restrict__ AH, const _Float16* __restrict__ BH,
    const float* __restrict__ X1, float* __restrict__ O2)
{
  __shared__ _Float16 sA[128 * 32];
  __shared__ _Float16 sB[64 * 32];
  const int t = threadIdx.x;
  const int bn = blockIdx.x, bm = blockIdx.y;
  const int lane = t & 63, wv = t >> 6, quad = lane >> 4, l16 = lane & 15;
  const int srowA = wv * 32 + (lane >> 2);
  const int srowB = wv * 16 + (lane >> 2);
  const int scol = (lane & 3) * 8;
  floatx4 acc[2][4] = {};
  const _Float16* gA = AH + (size_t)(bm * 128 + srowA) * 1024 + scol;
  const _Float16* gB = BH + (size_t)(bn * 64 + srowB) * 1024 + scol;
  for (int kt = 0; kt < 32; kt++) {
    __syncthreads();
    STAGE16(gA + kt * 32,         &sA[(wv * 32) * 32]);
    STAGE16(gA + kt * 32 + 16384, &sA[(wv * 32 + 16) * 32]);
    STAGE16(gB + kt * 32,         &sB[(wv * 16) * 32]);
    __syncthreads();
    half8 af[2], bf[4];
#pragma unroll
    for (int s = 0; s < 2; s++)
      af[s] = *(const half8*)&sA[(wv * 32 + s * 16 + l16) * 32 + quad * 8];
#pragma unroll
    for (int u = 0; u < 4; u++)
      bf[u] = *(const half8*)&sB[(u * 16 + l16) * 32 + quad * 8];
#pragma unroll
    for (int s = 0; s < 2; s++)
#pragma unroll
      for (int u = 0; u < 4; u++)
        acc[s][u] = __builtin_amdgcn_mfma_f32_16x16x32_f16(af[s], bf[u],
                                                           acc[s][u], 0, 0, 0);
  }
#pragma unroll
  for (int s = 0; s < 2; s++)
#pragma unroll
    for (int rr = 0; rr < 4; rr++) {
      const int row = bm * 128 + wv * 32 + s * 16 + quad * 4 + rr;
#pragma unroll
      for (int u = 0; u < 4; u++) {
        const size_t idx = (size_t)row * 1024 + bn * 64 + u * 16 + l16;
        const float hv = acc[s][u][rr];
        const float ge = 0.5f * hv * (1.0f + erff(hv * 0.70710678118654752f));
        O2[idx] = X1[idx] + ge;   // masked rows: X1=0 -> 0 (matches ref)
      }
    }
}

// ---------------------------------------------------------------------------
// V transpose: Vh[b,k,h*64+d] -> Vt[(b*16+h)*64+d][k] (64x64 LDS tile).
// ---------------------------------------------------------------------------
__global__ __launch_bounds__(256) void v_transpose(
    const _Float16* __restrict__ Vh, _Float16* __restrict__ Vt)
{
  __shared__ _Float16 sT[64 * AST];
  const int t = threadIdx.x;
  const int kt = blockIdx.x, bh = blockIdx.y;
  const int b = bh >> 4, h = bh & 15;
  const int r = t >> 2, c0 = (t & 3) * 16;
  const _Float16* src = Vh + (size_t)(b * 1024 + kt * 64 + r) * 1024 + h * 64 + c0;
  *(half8*)&sT[r * AST + c0] = *(const half8*)src;
  *(half8*)&sT[r * AST + c0 + 8] = *(const half8*)(src + 8);
  __syncthreads();
  half8 o0, o1;
#pragma unroll
  for (int j = 0; j < 8; j++) o0[j] = sT[(c0 + j) * AST + r];
#pragma unroll
  for (int j = 0; j < 8; j++) o1[j] = sT[(c0 + 8 + j) * AST + r];
  _Float16* dst = Vt + ((size_t)bh * 64 + r) * 1024 + kt * 64 + c0;
  *(half8*)dst = o0;
  *(half8*)(dst + 8) = o1;
}

// ---------------------------------------------------------------------------
// MFMA flash attention v3: S^T = K.Q^T formulation.
//   - softmax per column q = per-LANE (15 reg-max + 2 xor-shuffles over quads)
//   - P^T packs along k -> 4x ds_write_b64 per kt (was 16x b16)
//   - PV: A=P (rows q from wave-private LDS), B=V^T -> O in C-layout rows q.
// Block = 64 q-rows of one (b,h); f16 Qh for staging AND residual.
// ---------------------------------------------------------------------------
__global__ __launch_bounds__(256) void attn_mfma3(
    const _Float16* __restrict__ Qh, const _Float16* __restrict__ Kh,
    const _Float16* __restrict__ Vt, const int* __restrict__ maskQ,
    const int* __restrict__ maskK, float* __restrict__ O1)
{
  __shared__ _Float16 sK[64 * AST];
  __shared__ _Float16 sV[64 * AST];
  __shared__ _Float16 sQP[64 * AST];   // Q tile at start; per-wave P rows in loop
  __shared__ float bias[1024];

  const int t = threadIdx.x;
  const int qt = blockIdx.x, bh = blockIdx.y;
  const int b = bh >> 4, h = bh & 15;
  const int q0 = qt * 64;
  const size_t base = (size_t)b * 1024;
  const int wv = t >> 6, lane = t & 63, quad = lane >> 4, l16 = lane & 15;
  const int r = t >> 2, c0 = (t & 3) * 16;

  for (int i = t; i < 1024; i += 256)
    bias[i] = maskK[b * 1024 + i] ? -1e30f : 0.0f;

  {  // stage Q tile (pure f16 copy)
    const _Float16* qp = Qh + (base + q0 + r) * 1024 + h * 64 + c0;
    *(half8*)&sQP[r * AST + c0] = *(const half8*)qp;
    *(half8*)&sQP[r * AST + c0 + 8] = *(const half8*)(qp + 8);
  }
  __syncthreads();

  // Q B-operand frags (wave's 16 q = wv*16 + l16), held in regs for whole loop
  const half8 bq0 = *(const half8*)&sQP[(wv * 16 + l16) * AST + quad * 8];
  const half8 bq1 = *(const half8*)&sQP[(wv * 16 + l16) * AST + 32 + quad * 8];

  float m_i = -1e30f, l_i = 0.0f;      // per-lane: column q = wv*16 + l16
  floatx4 acc_o[4] = {};               // O C-layout: row q=quad*4+rr, col d=nt*16+l16

  for (int kt = 0; kt < 16; kt++) {
    __syncthreads();
    {
      const _Float16* kp = Kh + (base + kt * 64 + r) * 1024 + h * 64 + c0;
      const _Float16* vp = Vt + ((size_t)bh * 64 + r) * 1024 + kt * 64 + c0;
      const half8 k0v = *(const half8*)kp;
      const half8 k1v = *(const half8*)(kp + 8);
      const half8 v0v = *(const half8*)vp;
      const half8 v1v = *(const half8*)(vp + 8);
      *(half8*)&sK[r * AST + c0] = k0v;
      *(half8*)&sK[r * AST + c0 + 8] = k1v;
      *(half8*)&sV[r * AST + c0] = v0v;
      *(half8*)&sV[r * AST + c0 + 8] = v1v;
    }
    __syncthreads();

    // S^T[k][q]: A = K rows, B = Q rows. s[mt][rr]: k = mt*16+quad*4+rr, q = wv*16+l16
    floatx4 s[4] = {};
#pragma unroll
    for (int mt = 0; mt < 4; mt++) {
      const half8 ak0 = *(const half8*)&sK[(mt * 16 + l16) * AST + quad * 8];
      const half8 ak1 = *(const half8*)&sK[(mt * 16 + l16) * AST + 32 + quad * 8];
      s[mt] = __builtin_amdgcn_mfma_f32_16x16x32_f16(ak0, bq0, s[mt], 0, 0, 0);
      s[mt] = __builtin_amdgcn_mfma_f32_16x16x32_f16(ak1, bq1, s[mt], 0, 0, 0);
    }
#pragma unroll
    for (int mt = 0; mt < 4; mt++) {
      const float4 b4 = *(const float4*)&bias[kt * 64 + mt * 16 + quad * 4];
      s[mt][0] = s[mt][0] * 0.03125f + b4.x;
      s[mt][1] = s[mt][1] * 0.03125f + b4.y;
      s[mt][2] = s[mt][2] * 0.03125f + b4.z;
      s[mt][3] = s[mt][3] * 0.03125f + b4.w;
    }

    // column max (16 regs + 2 quad-shuffles), online-softmax state per lane
    float mx = -1e30f;
#pragma unroll
    for (int mt = 0; mt < 4; mt++)
      mx = fmaxf(mx, fmaxf(fmaxf(s[mt][0], s[mt][1]), fmaxf(s[mt][2], s[mt][3])));
    mx = fmaxf(mx, __shfl_xor(mx, 16));
    mx = fmaxf(mx, __shfl_xor(mx, 32));
    const float mn = fmaxf(m_i, mx);
    const float alpha = __expf(m_i - mn);
    m_i = mn;

    float rsum = 0.0f;
#pragma unroll
    for (int mt = 0; mt < 4; mt++)
#pragma unroll
      for (int rr = 0; rr < 4; rr++) {
        const float sv = s[mt][rr];
        const float p = (sv <= -1e20f) ? 0.0f : __expf(sv - mn);
        s[mt][rr] = p;
        rsum += p;
      }
    rsum += __shfl_xor(rsum, 16);
    rsum += __shfl_xor(rsum, 32);
    l_i = l_i * alpha + rsum;

    // broadcast alpha (indexed by column q) to O rows (q = quad*4+rr)
    float al[4];
#pragma unroll
    for (int rr = 0; rr < 4; rr++) al[rr] = __shfl(alpha, quad * 4 + rr);
#pragma unroll
    for (int nt = 0; nt < 4; nt++)
#pragma unroll
      for (int rr = 0; rr < 4; rr++)
        acc_o[nt][rr] *= al[rr];

    // P^T -> wave-private LDS rows q, packed half4 along k (4x b64 writes)
#pragma unroll
    for (int mt = 0; mt < 4; mt++) {
      half4v pv;
      pv[0] = (_Float16)s[mt][0]; pv[1] = (_Float16)s[mt][1];
      pv[2] = (_Float16)s[mt][2]; pv[3] = (_Float16)s[mt][3];
      *(half4v*)&sQP[(wv * 16 + l16) * AST + mt * 16 + quad * 4] = pv;
    }

    // PV: A = P rows q, B = V^T rows d
    const half8 ap0 = *(const half8*)&sQP[(wv * 16 + l16) * AST + quad * 8];
    const half8 ap1 = *(const half8*)&sQP[(wv * 16 + l16) * AST + 32 + quad * 8];
#pragma unroll
    for (int nt = 0; nt < 4; nt++) {
      const half8 bv0 = *(const half8*)&sV[(nt * 16 + l16) * AST + quad * 8];
      const half8 bv1 = *(const half8*)&sV[(nt * 16 + l16) * AST + 32 + quad * 8];
      acc_o[nt] = __builtin_amdgcn_mfma_f32_16x16x32_f16(ap0, bv0, acc_o[nt], 0, 0, 0);
      acc_o[nt] = __builtin_amdgcn_mfma_f32_16x16x32_f16(ap1, bv1, acc_o[nt], 0, 0, 0);
    }
  }

  // epilogue: O1 = maskQ ? 0 : Qh + O/l   (l broadcast column->row like alpha)
  float il[4];
#pragma unroll
  for (int rr = 0; rr < 4; rr++) {
    const float lq = __shfl(l_i, quad * 4 + rr);
    il[rr] = (lq > 0.0f) ? 1.0f / lq : 0.0f;
  }
#pragma unroll
  for (int rr = 0; rr < 4; rr++) {
    const int row = q0 + wv * 16 + quad * 4 + rr;
    const int mq = maskQ[b * 1024 + row];
#pragma unroll
    for (int nt = 0; nt < 4; nt++) {
      const size_t gi = (base + row) * 1024 + h * 64 + nt * 16 + l16;
      O1[gi] = mq ? 0.0f : ((float)Qh[gi] + acc_o[nt][rr] * il[rr]);
    }
  }
}

// ---------------------------------------------------------------------------
// LayerNorm (one row of 1024 per block), fp32 in; fp32 out (+ optional f16).
// ---------------------------------------------------------------------------
__device__ __forceinline__ void ln_stats(float4 x, int t, float* mean, float* rinv) {
  float s = x.x + x.y + x.z + x.w;
  float s2 = x.x * x.x + x.y * x.y + x.z * x.z + x.w * x.w;
#pragma unroll
  for (int off = 32; off >= 1; off >>= 1) { s += __shfl_xor(s, off); s2 += __shfl_xor(s2, off); }
  __shared__ float red[8];
  __shared__ float sm[2];
  const int wv = t >> 6, lane = t & 63;
  if (lane == 0) { red[wv] = s; red[4 + wv] = s2; }
  __syncthreads();
  if (t == 0) {
    const float S = red[0] + red[1] + red[2] + red[3];
    const float S2 = red[4] + red[5] + red[6] + red[7];
    const float m = S * (1.0f / 1024.0f);
    const float v = S2 * (1.0f / 1024.0f) - m * m;
    sm[0] = m; sm[1] = rsqrtf(v + 1e-5f);
  }
  __syncthreads();
  *mean = sm[0]; *rinv = sm[1];
}

__global__ __launch_bounds__(256) void ln_f32(
    const float* __restrict__ X, const float* __restrict__ g,
    const float* __restrict__ bta, const int* __restrict__ mask,
    float* __restrict__ out)
{
  const int rr = blockIdx.x, t = threadIdx.x, c = 4 * t;
  const float4 x = *(const float4*)&X[(size_t)rr * 1024 + c];
  float mean, ri;
  ln_stats(x, t, &mean, &ri);
  const int msk = mask[rr];
  const float4 gg = *(const float4*)&g[c];
  const float4 bb = *(const float4*)&bta[c];
  float4 o;
  o.x = msk ? 0.f : (x.x - mean) * ri * gg.x + bb.x;
  o.y = msk ? 0.f : (x.y - mean) * ri * gg.y + bb.y;
  o.z = msk ? 0.f : (x.z - mean) * ri * gg.z + bb.z;
  o.w = msk ? 0.f : (x.w - mean) * ri * gg.w + bb.w;
  *(float4*)&out[(size_t)rr * 1024 + c] = o;
}

__global__ __launch_bounds__(256) void ln_f32h(
    const float* __restrict__ X, const float* __restrict__ g,
    const float* __restrict__ bta, const int* __restrict__ mask,
    float* __restrict__ out, _Float16* __restrict__ outh)
{
  const int rr = blockIdx.x, t = threadIdx.x, c = 4 * t;
  const float4 x = *(const float4*)&X[(size_t)rr * 1024 + c];
  float mean, ri;
  ln_stats(x, t, &mean, &ri);
  const int msk = mask[rr];
  const float4 gg = *(const float4*)&g[c];
  const float4 bb = *(const float4*)&bta[c];
  float4 o;
  o.x = msk ? 0.f : (x.x - mean) * ri * gg.x + bb.x;
  o.y = msk ? 0.f : (x.y - mean) * ri * gg.y + bb.y;
  o.z = msk ? 0.f : (x.z - mean) * ri * gg.z + bb.z;
  o.w = msk ? 0.f : (x.w - mean) * ri * gg.w + bb.w;
  const size_t idx = (size_t)rr * 1024 + c;
  *(float4*)&out[idx] = o;
  half4v hh;
  hh[0] = (_Float16)o.x; hh[1] = (_Float16)o.y;
  hh[2] = (_Float16)o.z; hh[3] = (_Float16)o.w;
  *(half4v*)&outh[idx] = hh;
}

// ---------------------------------------------------------------------------
extern "C" void kernel_launch(void* const* d_in, const int* in_sizes, int n_in,
                              void* d_out, int out_size, void* d_ws, size_t ws_size,
                              hipStream_t stream)
{
  const float* Q  = (const float*)d_in[0];
  const float* K  = (const float*)d_in[1];
  const float* V  = (const float*)d_in[2];
  const float* Wq = (const float*)d_in[3];
  const float* Wk = (const float*)d_in[4];
  const float* Wv = (const float*)d_in[5];
  const float* Wo = (const float*)d_in[6];
  const float* g1 = (const float*)d_in[7];
  const float* b1 = (const float*)d_in[8];
  const float* g2 = (const float*)d_in[9];
  const float* b2 = (const float*)d_in[10];
  float* out = (float*)d_out;

  char* base = (char*)d_ws;
  const size_t MB_ = 1024 * 1024;
  _Float16* Xq  = (_Float16*)(base +  0 * MB_);   // [0,8)
  _Float16* Xk  = (_Float16*)(base +  8 * MB_);   // [8,16)
  _Float16* Xv  = (_Float16*)(base + 16 * MB_);   // [16,24)
  _Float16* Wqh = (_Float16*)(base + 24 * MB_);   // [24,26)
  _Float16* Wkh = (_Float16*)(base + 26 * MB_);   // [26,28)
  _Float16* Wvh = (_Float16*)(base + 28 * MB_);   // [28,30)
  _Float16* Woh = (_Float16*)(base + 30 * MB_);   // [30,32)
  _Float16* Qh  = (_Float16*)(base + 32 * MB_);   // [32,40)
  _Float16* Kh  = (_Float16*)(base + 40 * MB_);   // [40,48)
  _Float16* Vh  = (_Float16*)(base + 48 * MB_);   // [48,56)
  _Float16* Vt  = (_Float16*)(base + 56 * MB_);   // [56,64)
  float*    O1  = (float*)(base + 64 * MB_);      // [64,80)
  int*      mQ  = (int*)(base + 80 * MB_);
  int*      mK  = mQ + NTOK;                      // peak: 80 MB + 32 KB (r8-proven)
  // post-attention aliases (source regions dead):
  float*    X1  = (float*)(base + 0 * MB_);       // over Xq∪Xk
  _Float16* X1h = (_Float16*)(base + 16 * MB_);   // over Xv
  float*    O2  = (float*)(base + 32 * MB_);      // over Qh∪Kh

  const dim3 bb(256);
  mask_prep<<<dim3(16), bb, 0, stream>>>((const int*)d_in[11], (const int*)d_in[12], mQ, mK);
  cvt_all<<<dim3(8192), bb, 0, stream>>>(Q, K, V, Wq, Wk, Wv, Wo,
                                         Xq, Xk, Xv, Wqh, Wkh, Wvh, Woh);
  qkv_gemm<<<dim3(8, 32, 3), bb, 0, stream>>>(Xq, Xk, Xv, Wqh, Wkh, Wvh,
                                              mQ, mK, Qh, Kh, Vh);
  v_transpose<<<dim3(16, 64), bb, 0, stream>>>(Vh, Vt);
  attn_mfma3<<<dim3(16, 64), bb, 0, stream>>>(Qh, Kh, Vt, mQ, mK, O1);
  ln_f32h<<<dim3(4096), bb, 0, stream>>>(O1, g1, b1, mQ, X1, X1h);
  gemm_wo<<<dim3(16, 32), bb, 0, stream>>>(X1h, Woh, X1, O2);
  ln_f32<<<dim3(4096), bb, 0, stream>>>(O2, g2, b2, mQ, out);
}